// Round 7
// baseline (276.572 us; speedup 1.0000x reference)
//
#include <hip/hip_runtime.h>
#include <math.h>

#define NB      512
#define NELEC   30
#define NATOMS  10
#define NNEN    40      // en graph nodes: 30 electrons + 10 atoms
#define FEAT    64
#define KRBF    64
#define BLOCK   1024    // 16 waves/CU (1 block/CU by LDS)
#define NWAVES  (BLOCK/64)
#define NPEE    435     // unique elec-elec pairs
#define NPEN    300     // unique elec-nuc pairs
#define QF      16      // features per quarter: acc[16] = hard cap on live regs
#define FPAD    65      // filt row stride: lanes read (65p+f), 2-way banks = free

// ---------------- LDS layouts (in floats) ----------------
// ee: xyz[96] | h[30*64] | agg[30*64] | filt[435*65]
#define EE_H     96
#define EE_AGG   (EE_H + NELEC*FEAT)
#define EE_FILT  (EE_AGG + NELEC*FEAT)
#define EE_TOTAL (EE_FILT + NPEE*FPAD)          // 32211 floats = 128844 B -> 1 block/CU
// en: xyz[96] | h[40*64] | agg[40*64] | filt[300*65]
#define EN_H     96
#define EN_AGG   (EN_H + NNEN*FEAT)
#define EN_FILT  (EN_AGG + NNEN*FEAT)
#define EN_TOTAL (EN_FILT + NPEN*FPAD)          // 24716 floats = 98864 B  -> 1 block/CU

// R2-R6 lesson: the allocator pins 64 VGPRs regardless of occupancy hints;
// any >~24-float live accumulator spills to scratch (R6: 65MB WRITE_SIZE).
// Design rule: peak per-thread live state <= 16 floats, everywhere.
#define KERNEL_ATTRS __attribute__((amdgpu_flat_work_group_size(BLOCK, BLOCK)))

// triangular pair index base for row i (i<j pairs of 30 electrons)
__device__ __forceinline__ int ee_base(int i) { return 29*i - ((i*(i-1))>>1); }

// ==========================================================================
// elec-elec GNN: one block per batch. Writes partial log-Jastrow (double).
// Filter: wave w -> feature-quarter q=w&3 (wave-uniform => wf row quarter is
// an s_load into SGPRs, reused by 64 lanes) and pairs (w>>2)*64+lane+pass*256.
// acc[16] local, tanh'd and stored immediately. FP chains per (pair,feature)
// bit-identical to the R1 passing kernel.
// ==========================================================================
__global__ KERNEL_ATTRS
void ee_kernel(const float* __restrict__ pos,
               const float* __restrict__ emb,
               const float* __restrict__ wf,
               const float* __restrict__ bf,
               const float* __restrict__ wl,
               const float* __restrict__ bl,
               const float* __restrict__ wr,
               const float* __restrict__ br,
               const int*   __restrict__ types,
               double*      __restrict__ kout)
{
    extern __shared__ float sm[];
    float* xyz  = sm;            // [96]
    float* hS   = sm + EE_H;     // [30][64]
    float* aggS = sm + EE_AGG;   // [30][64]
    float* fS   = sm + EE_FILT;  // [435][65]

    const int tid  = threadIdx.x;
    const int b    = blockIdx.x;
    const int lane = tid & 63;
    const int w    = tid >> 6;

    // stage positions; init h = emb[types]
    for (int idx = tid; idx < NELEC*3; idx += BLOCK) xyz[idx] = pos[b*NELEC*3 + idx];
    for (int idx = tid; idx < NELEC*FEAT; idx += BLOCK) {
        int n = idx >> 6, f = idx & 63;
        hS[idx] = emb[types[n]*FEAT + f];
    }
    __syncthreads();

    // ---- filter GEMM: wave=(quarter q, pair-group), 2 pair passes ----
    {
        const int q  = __builtin_amdgcn_readfirstlane(w & 3);   // wave-uniform
        const int pg = w >> 2;                                   // 0..3
        #pragma unroll
        for (int pass = 0; pass < 2; ++pass) {
            int p = pass*256 + pg*64 + lane;
            p = (p < NPEE) ? p : (NPEE - 1);                     // clamp: dup bits ok
            int i = 0, rem = p;
            while (rem >= NELEC - 1 - i) { rem -= NELEC - 1 - i; ++i; }
            const int j = i + 1 + rem;
            const float dx = xyz[3*i+0] - xyz[3*j+0];
            const float dy = xyz[3*i+1] - xyz[3*j+1];
            const float dz = xyz[3*i+2] - xyz[3*j+2];
            const float dd = sqrtf(dx*dx + dy*dy + dz*dz);

            float acc[QF];
            const float* bfq = bf + q*QF;                        // s_load
            #pragma unroll
            for (int f = 0; f < QF; ++f) acc[f] = bfq[f];
            #pragma unroll 2
            for (int k = 0; k < KRBF; ++k) {
                const float ck = (float)((double)k * (8.0/63.0));
                const float t  = dd - ck;
                const float rk = expf(-t*t);
                const float* wrow = wf + k*FEAT + q*QF;          // s_load_dwordx16
                #pragma unroll
                for (int f = 0; f < QF; ++f) acc[f] = fmaf(rk, wrow[f], acc[f]);
            }
            #pragma unroll
            for (int f = 0; f < QF; ++f)
                fS[p*FPAD + q*QF + f] = tanhf(acc[f]);
        }
    }
    __syncthreads();

    // ---- interaction layers ----
    for (int l = 0; l < 2; ++l) {
        const float* wlL = wl + l*FEAT*FEAT;
        const float* blL = bl + l*FEAT;

        // messages: (i,f) items = 1920, two passes of 1024
        #pragma unroll
        for (int pass = 0; pass < 2; ++pass) {
            const int idx = tid + pass*BLOCK;
            if (idx < NELEC*FEAT) {
                const int i = idx >> 6;
                const int f = idx & 63;
                float a = 0.f;
                #pragma unroll
                for (int j = 0; j < NELEC; ++j) {
                    if (j != i) {
                        int pp = (j < i) ? (ee_base(j) + (i - j - 1))
                                         : (ee_base(i) + (j - i - 1));
                        a = fmaf(hS[j*FEAT + f], fS[pp*FPAD + f], a);
                    }
                }
                aggS[i*FEAT + f] = a;
            }
        }
        __syncthreads();

        // h += tanh(agg @ wl + bl)   (lane = feature, wave-strided nodes)
        for (int i = w; i < NELEC; i += NWAVES) {
            float a2 = 0.f;
            const float4* arow = reinterpret_cast<const float4*>(aggS + i*FEAT);
            #pragma unroll
            for (int k = 0; k < FEAT/4; ++k) {
                float4 av = arow[k];                      // broadcast b128
                a2 = fmaf(av.x, wlL[(4*k+0)*FEAT + lane], a2);
                a2 = fmaf(av.y, wlL[(4*k+1)*FEAT + lane], a2);
                a2 = fmaf(av.z, wlL[(4*k+2)*FEAT + lane], a2);
                a2 = fmaf(av.w, wlL[(4*k+3)*FEAT + lane], a2);
            }
            hS[i*FEAT + lane] += tanhf(a2 + blL[lane]);
        }
        __syncthreads();
    }

    // ---- readout: (sum_n h[n]) . wr + br   (f64 tail) ----
    if (w == 0) {
        float s = 0.f;
        #pragma unroll
        for (int n = 0; n < NELEC; ++n) s += hS[n*FEAT + lane];
        double dv = (double)s * (double)wr[lane];
        #pragma unroll
        for (int o = 32; o > 0; o >>= 1) dv += __shfl_xor(dv, o, 64);
        if (lane == 0) kout[b] = dv + (double)br[0];
    }
}

// ==========================================================================
// elec-nuc GNN + final combine: out[b] = exp(k_ee + k_en)
// ==========================================================================
__global__ KERNEL_ATTRS
void en_kernel(const float* __restrict__ pos,
               const float* __restrict__ atoms,
               const float* __restrict__ emb,
               const float* __restrict__ wf,
               const float* __restrict__ bf,
               const float* __restrict__ wl,
               const float* __restrict__ bl,
               const float* __restrict__ wr,
               const float* __restrict__ br,
               const int*   __restrict__ types,
               const double* __restrict__ kin,
               float*       __restrict__ out)
{
    extern __shared__ float sm[];
    float* xyz  = sm;            // [96]
    float* hS   = sm + EN_H;     // [40][64]
    float* aggS = sm + EN_AGG;   // [40][64]
    float* fS   = sm + EN_FILT;  // [300][65]

    const int tid  = threadIdx.x;
    const int b    = blockIdx.x;
    const int lane = tid & 63;
    const int w    = tid >> 6;

    for (int idx = tid; idx < NELEC*3; idx += BLOCK) xyz[idx] = pos[b*NELEC*3 + idx];
    for (int idx = tid; idx < NNEN*FEAT; idx += BLOCK) {
        int n = idx >> 6, f = idx & 63;
        hS[idx] = emb[types[n]*FEAT + f];
    }
    __syncthreads();

    // ---- filter GEMM: pair q2 = a*30 + e (atom-major); wave=(quarter, pg) ----
    {
        const int q  = __builtin_amdgcn_readfirstlane(w & 3);
        const int pg = w >> 2;
        #pragma unroll
        for (int pass = 0; pass < 2; ++pass) {
            int p = pass*256 + pg*64 + lane;
            p = (p < NPEN) ? p : (NPEN - 1);
            const int a = p / NELEC;
            const int e = p - a*NELEC;
            const float dx = xyz[3*e+0] - atoms[3*a+0];
            const float dy = xyz[3*e+1] - atoms[3*a+1];
            const float dz = xyz[3*e+2] - atoms[3*a+2];
            const float dd = sqrtf(dx*dx + dy*dy + dz*dz);

            float acc[QF];
            const float* bfq = bf + q*QF;
            #pragma unroll
            for (int f = 0; f < QF; ++f) acc[f] = bfq[f];
            #pragma unroll 2
            for (int k = 0; k < KRBF; ++k) {
                const float ck = (float)((double)k * (8.0/63.0));
                const float t  = dd - ck;
                const float rk = expf(-t*t);
                const float* wrow = wf + k*FEAT + q*QF;
                #pragma unroll
                for (int f = 0; f < QF; ++f) acc[f] = fmaf(rk, wrow[f], acc[f]);
            }
            #pragma unroll
            for (int f = 0; f < QF; ++f)
                fS[p*FPAD + q*QF + f] = tanhf(acc[f]);
        }
    }
    __syncthreads();

    for (int l = 0; l < 2; ++l) {
        const float* wlL = wl + l*FEAT*FEAT;
        const float* blL = bl + l*FEAT;

        // bipartite messages: (n,f) items = 2560, three passes
        #pragma unroll
        for (int pass = 0; pass < 3; ++pass) {
            const int idx = tid + pass*BLOCK;
            if (idx < NNEN*FEAT) {
                const int n = idx >> 6;
                const int f = idx & 63;
                float a = 0.f;
                if (n < NELEC) {            // electron node: atoms ascending
                    #pragma unroll
                    for (int at = 0; at < NATOMS; ++at)
                        a = fmaf(hS[(NELEC+at)*FEAT + f],
                                 fS[(at*NELEC + n)*FPAD + f], a);
                } else {                    // atom node: electrons ascending
                    const int at = n - NELEC;
                    #pragma unroll
                    for (int e2 = 0; e2 < NELEC; ++e2)
                        a = fmaf(hS[e2*FEAT + f],
                                 fS[(at*NELEC + e2)*FPAD + f], a);
                }
                aggS[n*FEAT + f] = a;
            }
        }
        __syncthreads();

        for (int n = w; n < NNEN; n += NWAVES) {
            float a2 = 0.f;
            const float4* arow = reinterpret_cast<const float4*>(aggS + n*FEAT);
            #pragma unroll
            for (int k = 0; k < FEAT/4; ++k) {
                float4 av = arow[k];
                a2 = fmaf(av.x, wlL[(4*k+0)*FEAT + lane], a2);
                a2 = fmaf(av.y, wlL[(4*k+1)*FEAT + lane], a2);
                a2 = fmaf(av.z, wlL[(4*k+2)*FEAT + lane], a2);
                a2 = fmaf(av.w, wlL[(4*k+3)*FEAT + lane], a2);
            }
            hS[n*FEAT + lane] += tanhf(a2 + blL[lane]);
        }
        __syncthreads();
    }

    if (w == 0) {
        float s = 0.f;
        #pragma unroll
        for (int n = 0; n < NNEN; ++n) s += hS[n*FEAT + lane];
        double dv = (double)s * (double)wr[lane];
        #pragma unroll
        for (int o = 32; o > 0; o >>= 1) dv += __shfl_xor(dv, o, 64);
        if (lane == 0) out[b] = (float)exp(dv + (double)br[0] + kin[b]);
    }
}

// ==========================================================================
extern "C" void kernel_launch(void* const* d_in, const int* in_sizes, int n_in,
                              void* d_out, int out_size, void* d_ws, size_t ws_size,
                              hipStream_t stream) {
    const float* pos    = (const float*)d_in[0];
    const float* atoms  = (const float*)d_in[1];
    const float* emb_ee = (const float*)d_in[2];
    const float* wf_ee  = (const float*)d_in[3];
    const float* bf_ee  = (const float*)d_in[4];
    const float* wl_ee  = (const float*)d_in[5];
    const float* bl_ee  = (const float*)d_in[6];
    const float* wr_ee  = (const float*)d_in[7];
    const float* br_ee  = (const float*)d_in[8];
    const float* emb_en = (const float*)d_in[9];
    const float* wf_en  = (const float*)d_in[10];
    const float* bf_en  = (const float*)d_in[11];
    const float* wl_en  = (const float*)d_in[12];
    const float* bl_en  = (const float*)d_in[13];
    const float* wr_en  = (const float*)d_in[14];
    const float* br_en  = (const float*)d_in[15];
    const int*   ee_ty  = (const int*)d_in[18];
    const int*   en_ty  = (const int*)d_in[21];

    double* kws = (double*)d_ws;       // [512] partial log-Jastrow from ee
    float*  out = (float*)d_out;       // [512]

    (void)hipFuncSetAttribute((const void*)ee_kernel,
            hipFuncAttributeMaxDynamicSharedMemorySize, EE_TOTAL*(int)sizeof(float));
    (void)hipFuncSetAttribute((const void*)en_kernel,
            hipFuncAttributeMaxDynamicSharedMemorySize, EN_TOTAL*(int)sizeof(float));

    ee_kernel<<<NB, BLOCK, EE_TOTAL*sizeof(float), stream>>>(
        pos, emb_ee, wf_ee, bf_ee, wl_ee, bl_ee, wr_ee, br_ee, ee_ty, kws);
    en_kernel<<<NB, BLOCK, EN_TOTAL*sizeof(float), stream>>>(
        pos, atoms, emb_en, wf_en, bf_en, wl_en, bl_en, wr_en, br_en, en_ty, kws, out);
}

// Round 8
// 249.127 us; speedup vs baseline: 1.1102x; 1.1102x over previous
//
#include <hip/hip_runtime.h>
#include <math.h>

#define NB      512
#define NELEC   30
#define NATOMS  10
#define NNEN    40      // en graph nodes: 30 electrons + 10 atoms
#define FEAT    64
#define KRBF    64
#define BLOCK   512
#define NWAVES  (BLOCK/64)
#define NPEE    435     // unique elec-elec pairs
#define NPEN    300     // unique elec-nuc pairs
#define FPAD    65      // filt row padding (+1 float)

// ---------------- LDS layouts (floats); EN layout nests inside EE ----------
#define EE_H     96
#define EE_AGG   (EE_H + NELEC*FEAT)
#define EE_FILT  (EE_AGG + NELEC*FEAT)
#define EE_TOTAL (EE_FILT + NPEE*FPAD)          // 32659 floats = 130636 B
#define EN_H     96
#define EN_AGG   (EN_H + NNEN*FEAT)
#define EN_FILT  (EN_AGG + NNEN*FEAT)
#define EN_TOTAL (EN_FILT + NPEN*FPAD)          // 24716 floats = 98864 B (< EE_TOTAL)

// R1-R7 lesson: the R1 bodies with NO occupancy attributes are the only
// compiled artifacts proven spill-free (R1 ee: WRITE_SIZE 16 KB). This kernel
// is a pure concatenation of those two bodies; do not touch their code.
__device__ __forceinline__ int ee_base(int i) { return 29*i - ((i*(i-1))>>1); }

// ==========================================================================
// Fused: per block b, run R1-ee body (partial log-Jastrow kee in wave-0
// registers), barrier, then R1-en body reusing the same LDS, then
// out[b] = exp((dv_en + br_en) + kee)  -- same f64 associativity as R1.
// ==========================================================================
__global__ __launch_bounds__(BLOCK)
void fused_kernel(const float* __restrict__ pos,
                  const float* __restrict__ atoms,
                  const float* __restrict__ emb_ee,
                  const float* __restrict__ wf_ee,
                  const float* __restrict__ bf_ee,
                  const float* __restrict__ wl_ee,
                  const float* __restrict__ bl_ee,
                  const float* __restrict__ wr_ee,
                  const float* __restrict__ br_ee,
                  const float* __restrict__ emb_en,
                  const float* __restrict__ wf_en,
                  const float* __restrict__ bf_en,
                  const float* __restrict__ wl_en,
                  const float* __restrict__ bl_en,
                  const float* __restrict__ wr_en,
                  const float* __restrict__ br_en,
                  const int*   __restrict__ ee_ty,
                  const int*   __restrict__ en_ty,
                  float*       __restrict__ out)
{
    extern __shared__ float sm[];
    const int tid  = threadIdx.x;
    const int b    = blockIdx.x;
    const int lane = tid & 63;
    const int w    = tid >> 6;

    double kee = 0.0;   // wave-0 carries ee log-Jastrow across phases (2 VGPRs)

    // ======================= EE phase (verbatim R1) =======================
    {
        float* xyz  = sm;            // [96]
        float* hS   = sm + EE_H;     // [30][64]
        float* aggS = sm + EE_AGG;   // [30][64]
        float* fS   = sm + EE_FILT;  // [435][65]

        for (int idx = tid; idx < NELEC*3; idx += BLOCK) xyz[idx] = pos[b*NELEC*3 + idx];
        for (int idx = tid; idx < NELEC*FEAT; idx += BLOCK) {
            int n = idx >> 6, f = idx & 63;
            hS[idx] = emb_ee[ee_ty[n]*FEAT + f];
        }
        __syncthreads();

        // filter GEMM: one unique pair per lane (clamped -> uniform CF)
        {
            const int p = (tid < NPEE) ? tid : (NPEE - 1);
            int i = 0, rem = p;
            while (rem >= NELEC - 1 - i) { rem -= NELEC - 1 - i; ++i; }
            const int j = i + 1 + rem;
            const float dx = xyz[3*i+0] - xyz[3*j+0];
            const float dy = xyz[3*i+1] - xyz[3*j+1];
            const float dz = xyz[3*i+2] - xyz[3*j+2];
            const float dd = sqrtf(dx*dx + dy*dy + dz*dz);

            float acc[FEAT];
            #pragma unroll
            for (int f = 0; f < FEAT; ++f) acc[f] = bf_ee[f];   // uniform -> s_load
            #pragma unroll 2
            for (int k = 0; k < KRBF; ++k) {
                const float ck = (float)((double)k * (8.0/63.0));
                const float t  = dd - ck;
                const float rk = expf(-t*t);
                const float* wrow = wf_ee + k*FEAT;             // wave-uniform row
                #pragma unroll
                for (int f = 0; f < FEAT; ++f) acc[f] = fmaf(rk, wrow[f], acc[f]);
            }
            #pragma unroll
            for (int f = 0; f < FEAT; ++f) fS[p*FPAD + f] = tanhf(acc[f]);
        }
        __syncthreads();

        // interaction layers
        for (int l = 0; l < 2; ++l) {
            const float* wlL = wl_ee + l*FEAT*FEAT;
            const float* blL = bl_ee + l*FEAT;

            for (int i = w; i < NELEC; i += NWAVES) {
                float a = 0.f;
                // messages, j ascending (ref order); lane = feature
                // (R1 used (node,feat)-item mapping; this is the same op order
                //  per (i,f): j ascending fmaf chain)
                #pragma unroll
                for (int j = 0; j < NELEC; ++j) {
                    if (j != i) {
                        int pp = (j < i) ? (ee_base(j) + (i - j - 1))
                                         : (ee_base(i) + (j - i - 1));
                        a = fmaf(hS[j*FEAT + lane], fS[pp*FPAD + lane], a);
                    }
                }
                aggS[i*FEAT + lane] = a;
            }
            __syncthreads();

            for (int i = w; i < NELEC; i += NWAVES) {
                float a2 = 0.f;
                const float4* arow = reinterpret_cast<const float4*>(aggS + i*FEAT);
                #pragma unroll
                for (int k = 0; k < FEAT/4; ++k) {
                    float4 av = arow[k];                      // broadcast b128
                    a2 = fmaf(av.x, wlL[(4*k+0)*FEAT + lane], a2);
                    a2 = fmaf(av.y, wlL[(4*k+1)*FEAT + lane], a2);
                    a2 = fmaf(av.z, wlL[(4*k+2)*FEAT + lane], a2);
                    a2 = fmaf(av.w, wlL[(4*k+3)*FEAT + lane], a2);
                }
                hS[i*FEAT + lane] += tanhf(a2 + blL[lane]);
            }
            __syncthreads();
        }

        // readout: (sum_n h[n]) . wr + br (f64 tail) -> kee register (wave 0)
        if (w == 0) {
            float s = 0.f;
            #pragma unroll
            for (int n = 0; n < NELEC; ++n) s += hS[n*FEAT + lane];
            double dv = (double)s * (double)wr_ee[lane];
            #pragma unroll
            for (int o = 32; o > 0; o >>= 1) dv += __shfl_xor(dv, o, 64);
            kee = dv + (double)br_ee[0];
        }
    }
    __syncthreads();   // ee readout reads hS before en phase overwrites it

    // ======================= EN phase (verbatim R1) =======================
    {
        float* xyz  = sm;            // [96] (same content; rewrite same bits)
        float* hS   = sm + EN_H;     // [40][64]
        float* aggS = sm + EN_AGG;   // [40][64]
        float* fS   = sm + EN_FILT;  // [300][65]

        for (int idx = tid; idx < NELEC*3; idx += BLOCK) xyz[idx] = pos[b*NELEC*3 + idx];
        for (int idx = tid; idx < NNEN*FEAT; idx += BLOCK) {
            int n = idx >> 6, f = idx & 63;
            hS[idx] = emb_en[en_ty[n]*FEAT + f];
        }
        __syncthreads();

        // filter GEMM: pair q = a*30 + e (atom-major, matches ref ordering)
        {
            const int p = (tid < NPEN) ? tid : (NPEN - 1);
            const int a = p / NELEC;
            const int e = p - a*NELEC;
            const float dx = xyz[3*e+0] - atoms[3*a+0];
            const float dy = xyz[3*e+1] - atoms[3*a+1];
            const float dz = xyz[3*e+2] - atoms[3*a+2];
            const float dd = sqrtf(dx*dx + dy*dy + dz*dz);

            float acc[FEAT];
            #pragma unroll
            for (int f = 0; f < FEAT; ++f) acc[f] = bf_en[f];
            #pragma unroll 2
            for (int k = 0; k < KRBF; ++k) {
                const float ck = (float)((double)k * (8.0/63.0));
                const float t  = dd - ck;
                const float rk = expf(-t*t);
                const float* wrow = wf_en + k*FEAT;
                #pragma unroll
                for (int f = 0; f < FEAT; ++f) acc[f] = fmaf(rk, wrow[f], acc[f]);
            }
            #pragma unroll
            for (int f = 0; f < FEAT; ++f) fS[p*FPAD + f] = tanhf(acc[f]);
        }
        __syncthreads();

        for (int l = 0; l < 2; ++l) {
            const float* wlL = wl_en + l*FEAT*FEAT;
            const float* blL = bl_en + l*FEAT;

            for (int n = w; n < NNEN; n += NWAVES) {
                float a = 0.f;
                if (n < NELEC) {            // electron node: atoms ascending
                    #pragma unroll
                    for (int at = 0; at < NATOMS; ++at)
                        a = fmaf(hS[(NELEC+at)*FEAT + lane],
                                 fS[(at*NELEC + n)*FPAD + lane], a);
                } else {                    // atom node: electrons ascending
                    const int at = n - NELEC;
                    #pragma unroll
                    for (int e2 = 0; e2 < NELEC; ++e2)
                        a = fmaf(hS[e2*FEAT + lane],
                                 fS[(at*NELEC + e2)*FPAD + lane], a);
                }
                aggS[n*FEAT + lane] = a;
            }
            __syncthreads();

            for (int n = w; n < NNEN; n += NWAVES) {
                float a2 = 0.f;
                const float4* arow = reinterpret_cast<const float4*>(aggS + n*FEAT);
                #pragma unroll
                for (int k = 0; k < FEAT/4; ++k) {
                    float4 av = arow[k];
                    a2 = fmaf(av.x, wlL[(4*k+0)*FEAT + lane], a2);
                    a2 = fmaf(av.y, wlL[(4*k+1)*FEAT + lane], a2);
                    a2 = fmaf(av.z, wlL[(4*k+2)*FEAT + lane], a2);
                    a2 = fmaf(av.w, wlL[(4*k+3)*FEAT + lane], a2);
                }
                hS[n*FEAT + lane] += tanhf(a2 + blL[lane]);
            }
            __syncthreads();
        }

        // readout + final combine: out[b] = exp((dv_en + br_en) + kee)
        if (w == 0) {
            float s = 0.f;
            #pragma unroll
            for (int n = 0; n < NNEN; ++n) s += hS[n*FEAT + lane];
            double dv = (double)s * (double)wr_en[lane];
            #pragma unroll
            for (int o = 32; o > 0; o >>= 1) dv += __shfl_xor(dv, o, 64);
            if (lane == 0) out[b] = (float)exp(dv + (double)br_en[0] + kee);
        }
    }
}

// ==========================================================================
extern "C" void kernel_launch(void* const* d_in, const int* in_sizes, int n_in,
                              void* d_out, int out_size, void* d_ws, size_t ws_size,
                              hipStream_t stream) {
    const float* pos    = (const float*)d_in[0];
    const float* atoms  = (const float*)d_in[1];
    const float* emb_ee = (const float*)d_in[2];
    const float* wf_ee  = (const float*)d_in[3];
    const float* bf_ee  = (const float*)d_in[4];
    const float* wl_ee  = (const float*)d_in[5];
    const float* bl_ee  = (const float*)d_in[6];
    const float* wr_ee  = (const float*)d_in[7];
    const float* br_ee  = (const float*)d_in[8];
    const float* emb_en = (const float*)d_in[9];
    const float* wf_en  = (const float*)d_in[10];
    const float* bf_en  = (const float*)d_in[11];
    const float* wl_en  = (const float*)d_in[12];
    const float* bl_en  = (const float*)d_in[13];
    const float* wr_en  = (const float*)d_in[14];
    const float* br_en  = (const float*)d_in[15];
    const int*   ee_ty  = (const int*)d_in[18];
    const int*   en_ty  = (const int*)d_in[21];

    float* out = (float*)d_out;        // [512]

    (void)hipFuncSetAttribute((const void*)fused_kernel,
            hipFuncAttributeMaxDynamicSharedMemorySize, EE_TOTAL*(int)sizeof(float));

    fused_kernel<<<NB, BLOCK, EE_TOTAL*sizeof(float), stream>>>(
        pos, atoms,
        emb_ee, wf_ee, bf_ee, wl_ee, bl_ee, wr_ee, br_ee,
        emb_en, wf_en, bf_en, wl_en, bl_en, wr_en, br_en,
        ee_ty, en_ty, out);
}